// Round 2
// baseline (16217.120 us; speedup 1.0000x reference)
//
#include <hip/hip_runtime.h>
#include <math.h>

#define VOCAB 256
#define DD    256     // hidden/embed dim
#define BB    32      // batch
#define LL    2048    // seq len
#define G4    1024    // 4*DD gate width

__device__ __forceinline__ float sigf(float x) { return 1.0f / (1.0f + __expf(-x)); }

// ---------------------------------------------------------------------------
// Kernel A: gates_table[dir][v][j] = sum_k embed[v][k] * w_dir[k][j] + b_dir[j]
// (w rows 0..255 are Wx). 512 blocks: dir = bid>>8, v = bid&255.
// ---------------------------------------------------------------------------
__global__ __launch_bounds__(256) void k_table(
    const float* __restrict__ embed,
    const float* __restrict__ w_fwd, const float* __restrict__ b_fwd,
    const float* __restrict__ w_bwd, const float* __restrict__ b_bwd,
    float* __restrict__ tbl)
{
    const int dir = blockIdx.x >> 8;
    const int v   = blockIdx.x & 255;
    const float* __restrict__ w    = dir ? w_bwd : w_fwd;
    const float* __restrict__ bias = dir ? b_bwd : b_fwd;

    __shared__ __align__(16) float e[DD];
    const int tid = threadIdx.x;
    e[tid] = embed[v * DD + tid];
    __syncthreads();

    const float4* __restrict__ wx4 = (const float4*)w;  // [k][256] float4 groups
    float4 acc = ((const float4*)bias)[tid];
    #pragma unroll 2
    for (int k = 0; k < DD; k += 4) {
        float4 h4 = *(const float4*)&e[k];
        float4 w0 = wx4[(size_t)(k + 0) * 256 + tid];
        float4 w1 = wx4[(size_t)(k + 1) * 256 + tid];
        float4 w2 = wx4[(size_t)(k + 2) * 256 + tid];
        float4 w3 = wx4[(size_t)(k + 3) * 256 + tid];
        acc.x += h4.x * w0.x + h4.y * w1.x + h4.z * w2.x + h4.w * w3.x;
        acc.y += h4.x * w0.y + h4.y * w1.y + h4.z * w2.y + h4.w * w3.y;
        acc.z += h4.x * w0.z + h4.y * w1.z + h4.z * w2.z + h4.w * w3.z;
        acc.w += h4.x * w0.w + h4.y * w1.w + h4.z * w2.w + h4.w * w3.w;
    }
    ((float4*)tbl)[((size_t)dir * VOCAB + v) * 256 + tid] = acc;
}

// ---------------------------------------------------------------------------
// Kernel B: one block per (dir, batch) chain. 1024 threads:
//   g  = tid & 255  -> column group (4 contiguous gate cols 4g..4g+3)
//   kq = tid >> 8   -> k-quarter (64 of the 256 h dims)
// Phase A: partial matvec parts[kq][col] (skipped when h known zero).
// Phase B: threads 0..255 (d = tid) finish gates, update (c,h), write h to LDS,
//          reduce h . w_proj_slice -> pout[dir][b][t].
// Gate order i,g,f,o; forget bias +1; bwd resets state where t < len-1.
// ---------------------------------------------------------------------------
__global__ __launch_bounds__(1024) void k_scan(
    const int*   __restrict__ phonemes,
    const int*   __restrict__ lengths,
    const float* __restrict__ w_fwd,
    const float* __restrict__ w_bwd,
    const float* __restrict__ w_proj,
    const float* __restrict__ tbl,
    float* __restrict__ pout)
{
    const int dir = blockIdx.x >> 5;
    const int b   = blockIdx.x & 31;
    const int tid = threadIdx.x;
    const int g   = tid & 255;
    const int kq  = tid >> 8;

    const float4* __restrict__ wh4 = (const float4*)((dir ? w_bwd : w_fwd) + (size_t)DD * G4);
    const float*  __restrict__ tb  = tbl + (size_t)dir * VOCAB * G4;
    const int   len = lengths[b];
    const int* __restrict__ ph = phonemes + b * LL;
    float* __restrict__ pO = pout + ((size_t)dir * BB + b) * LL;

    __shared__ __align__(16) float h_lds[DD];
    __shared__ __align__(16) float parts[4][G4];
    __shared__ float red[4];

    float c  = 0.0f;
    float wp = 0.0f;
    if (tid < DD) wp = w_proj[dir * DD + tid];

    for (int s = 0; s < LL; ++s) {
        const int  t  = dir ? (LL - 1 - s) : s;
        const bool r  = dir && (t < len - 1);       // reset BEFORE step (bwd only)
        const bool hz = (s == 0) || r;              // h entering the step is zero

        if (!hz) {
            float4 acc = {0.f, 0.f, 0.f, 0.f};
            const int kbase = kq * 64;
            #pragma unroll 2
            for (int k = 0; k < 64; k += 4) {
                float4 h4 = *(const float4*)&h_lds[kbase + k];
                float4 w0 = wh4[(size_t)(kbase + k + 0) * 256 + g];
                float4 w1 = wh4[(size_t)(kbase + k + 1) * 256 + g];
                float4 w2 = wh4[(size_t)(kbase + k + 2) * 256 + g];
                float4 w3 = wh4[(size_t)(kbase + k + 3) * 256 + g];
                acc.x += h4.x * w0.x + h4.y * w1.x + h4.z * w2.x + h4.w * w3.x;
                acc.y += h4.x * w0.y + h4.y * w1.y + h4.z * w2.y + h4.w * w3.y;
                acc.z += h4.x * w0.z + h4.y * w1.z + h4.z * w2.z + h4.w * w3.z;
                acc.w += h4.x * w0.w + h4.y * w1.w + h4.z * w2.w + h4.w * w3.w;
            }
            *(float4*)&parts[kq][4 * g] = acc;
        }
        __syncthreads();

        if (tid < DD) {
            const int d = tid;
            const int v = ph[t];
            const float* __restrict__ trow = tb + (size_t)v * G4;
            float gi = trow[d];
            float gg = trow[DD + d];
            float gf = trow[2 * DD + d];
            float go = trow[3 * DD + d];
            if (!hz) {
                gi += parts[0][d]          + parts[1][d]          + parts[2][d]          + parts[3][d];
                gg += parts[0][DD + d]     + parts[1][DD + d]     + parts[2][DD + d]     + parts[3][DD + d];
                gf += parts[0][2 * DD + d] + parts[1][2 * DD + d] + parts[2][2 * DD + d] + parts[3][2 * DD + d];
                go += parts[0][3 * DD + d] + parts[1][3 * DD + d] + parts[2][3 * DD + d] + parts[3][3 * DD + d];
            }
            if (r) c = 0.0f;
            c = sigf(gf + 1.0f) * c + sigf(gi) * tanhf(gg);
            float h = sigf(go) * tanhf(c);
            h_lds[d] = h;

            float pc = h * wp;
            #pragma unroll
            for (int off = 32; off; off >>= 1) pc += __shfl_xor(pc, off);
            if ((tid & 63) == 0) red[tid >> 6] = pc;
        }
        __syncthreads();

        if (tid == 0) pO[t] = red[0] + red[1] + red[2] + red[3];
    }
}

// ---------------------------------------------------------------------------
// Kernel C: out[b,t] = relu(p_fwd + p_bwd + b_proj)
// ---------------------------------------------------------------------------
__global__ __launch_bounds__(256) void k_combine(
    const float* __restrict__ p,
    const float* __restrict__ b_proj,
    float* __restrict__ out)
{
    const int i = blockIdx.x * 256 + threadIdx.x;
    const float v = p[i] + p[BB * LL + i] + b_proj[0];
    out[i] = v > 0.0f ? v : 0.0f;
}

extern "C" void kernel_launch(void* const* d_in, const int* in_sizes, int n_in,
                              void* d_out, int out_size, void* d_ws, size_t ws_size,
                              hipStream_t stream)
{
    const int*   phon = (const int*)d_in[0];
    const int*   lens = (const int*)d_in[1];
    const float* emb  = (const float*)d_in[2];
    const float* wf   = (const float*)d_in[3];
    const float* bf   = (const float*)d_in[4];
    const float* wb   = (const float*)d_in[5];
    const float* bbi  = (const float*)d_in[6];
    const float* wp   = (const float*)d_in[7];
    const float* bp   = (const float*)d_in[8];
    float* out = (float*)d_out;

    float* ws  = (float*)d_ws;
    float* tbl = ws;                     // 2*256*1024      = 524288 floats (2 MB)
    float* p   = ws + 2 * VOCAB * G4;    // 2*32*2048       = 131072 floats (512 KB)

    k_table  <<<2 * VOCAB, 256, 0, stream>>>(emb, wf, bf, wb, bbi, tbl);
    k_scan   <<<64, 1024, 0, stream>>>(phon, lens, wf, wb, wp, tbl, p);
    k_combine<<<(BB * LL) / 256, 256, 0, stream>>>(p, bp, out);
}

// Round 3
// 10606.303 us; speedup vs baseline: 1.5290x; 1.5290x over previous
//
#include <hip/hip_runtime.h>
#include <math.h>

#define VOCAB 256
#define DD    256     // hidden/embed dim
#define BB    32      // batch
#define LL    2048    // seq len
#define G4    1024    // 4*DD gate width
#define NB    16      // blocks per direction
#define TPB   512

typedef __attribute__((ext_vector_type(8))) short short8;
typedef __attribute__((ext_vector_type(4))) float floatx4;

__device__ __forceinline__ float sigf(float x) { return 1.0f / (1.0f + __expf(-x)); }

__device__ __forceinline__ unsigned short f2bf(float x) {
    unsigned u = __builtin_bit_cast(unsigned, x);
    u = u + 0x7fffu + ((u >> 16) & 1u);
    return (unsigned short)(u >> 16);
}
__device__ __forceinline__ float bf2f(unsigned short b) {
    unsigned u = ((unsigned)b) << 16;
    return __builtin_bit_cast(float, u);
}

// ---------------------------------------------------------------------------
// Kernel A: gates_table[dir][v][j] = sum_k embed[v][k] * w_dir[k][j] + b_dir[j]
// ---------------------------------------------------------------------------
__global__ __launch_bounds__(256) void k_table(
    const float* __restrict__ embed,
    const float* __restrict__ w_fwd, const float* __restrict__ b_fwd,
    const float* __restrict__ w_bwd, const float* __restrict__ b_bwd,
    float* __restrict__ tbl)
{
    const int dir = blockIdx.x >> 8;
    const int v   = blockIdx.x & 255;
    const float* __restrict__ w    = dir ? w_bwd : w_fwd;
    const float* __restrict__ bias = dir ? b_bwd : b_fwd;

    __shared__ __align__(16) float e[DD];
    const int tid = threadIdx.x;
    e[tid] = embed[v * DD + tid];
    __syncthreads();

    const float4* __restrict__ wx4 = (const float4*)w;  // [k][256] float4 groups
    float4 acc = ((const float4*)bias)[tid];
    #pragma unroll 2
    for (int k = 0; k < DD; k += 4) {
        float4 h4 = *(const float4*)&e[k];
        float4 w0 = wx4[(size_t)(k + 0) * 256 + tid];
        float4 w1 = wx4[(size_t)(k + 1) * 256 + tid];
        float4 w2 = wx4[(size_t)(k + 2) * 256 + tid];
        float4 w3 = wx4[(size_t)(k + 3) * 256 + tid];
        acc.x += h4.x * w0.x + h4.y * w1.x + h4.z * w2.x + h4.w * w3.x;
        acc.y += h4.x * w0.y + h4.y * w1.y + h4.z * w2.y + h4.w * w3.y;
        acc.z += h4.x * w0.z + h4.y * w1.z + h4.z * w2.z + h4.w * w3.z;
        acc.w += h4.x * w0.w + h4.y * w1.w + h4.z * w2.w + h4.w * w3.w;
    }
    ((float4*)tbl)[((size_t)dir * VOCAB + v) * 256 + tid] = acc;
}

// ---------------------------------------------------------------------------
// k_zero: reset the cross-block barrier counters (ws is poisoned each launch)
// ---------------------------------------------------------------------------
__global__ void k_zero(int* __restrict__ ctr) {
    if (threadIdx.x < 2) ctr[threadIdx.x] = 0;
}

// ---------------------------------------------------------------------------
// k_scan_b: batched bidirectional LSTM scan.
// 32 blocks = 2 dirs x NB col-slices. Block (dir, j) owns hidden dims
// [16j, 16j+16) for ALL 32 batches; its 64 weight columns (4 gates x 16 dims)
// live permanently in VGPRs as bf16 hi/lo pairs. Per step:
//   poll barrier -> stage H(prev) to swizzled LDS (bf16 hi/lo, reset-zeroed)
//   -> 3-split MFMA (hhi*Whi + hlo*Whi + hhi*Wlo) -> gate exchange via LDS
//   -> c/h update (c persistent in regs) -> write h slice + proj partial
//   -> release-add barrier counter.
// ---------------------------------------------------------------------------
__global__ __launch_bounds__(TPB, 2) void k_scan_b(
    const int*   __restrict__ ph,
    const int*   __restrict__ lens,
    const float* __restrict__ w_fwd,
    const float* __restrict__ w_bwd,
    const float* __restrict__ w_proj,
    const float* __restrict__ tbl,
    float* __restrict__ Hbuf,
    float* __restrict__ pp,
    int*   __restrict__ ctr)
{
    const int dir  = blockIdx.x >> 4;
    const int j    = blockIdx.x & (NB - 1);
    const int tid  = threadIdx.x;
    const int lane = tid & 63;
    const int wv   = tid >> 6;        // wave 0..7
    const int mt   = wv >> 2;         // m-tile 0..1 (batches 16mt..16mt+15)
    const int gt   = wv & 3;          // gate 0..3 (i,g,f,o)

    const float* __restrict__ Wh = (dir ? w_bwd : w_fwd) + (size_t)DD * G4;
    const float* __restrict__ tb = tbl + (size_t)dir * VOCAB * G4;
    float* __restrict__ Hd = Hbuf + (size_t)dir * 2 * BB * DD;
    int* ctrd = ctr + dir;

    __shared__ unsigned short Ahi[BB * DD];   // 16KB, XOR-swizzled bf16 hi of H
    __shared__ unsigned short Alo[BB * DD];   // 16KB, lo
    __shared__ float gl[4][BB][16];           // 8KB gate exchange
    __shared__ int   ph_s[BB];

    // persistent cell state: this thread owns cell (b, dd)
    const int b     = tid >> 4;
    const int dd    = tid & 15;
    const int dglob = j * 16 + dd;
    float c = 0.0f;
    const int   lenb = lens[b];
    const float wpd  = w_proj[dir * DD + dglob];

    // ---- preload this wave's weight fragments into registers (bf16 split) ----
    short8 bhi[8], blo[8];
    {
        const int ccol  = gt * DD + j * 16 + (lane & 15);  // global gate column
        const int krow0 = 8 * (lane >> 4);
        #pragma unroll
        for (int kk = 0; kk < 8; ++kk) {
            short8 th, tl;
            #pragma unroll
            for (int e = 0; e < 8; ++e) {
                float wval = Wh[(size_t)(kk * 32 + krow0 + e) * G4 + ccol];
                unsigned short hi = f2bf(wval);
                th[e] = (short)hi;
                tl[e] = (short)f2bf(wval - bf2f(hi));
            }
            bhi[kk] = th;
            blo[kk] = tl;
        }
    }

    for (int s = 0; s < LL; ++s) {
        const int t = dir ? (LL - 1 - s) : s;

        // ---- barrier: wait until all NB blocks of this dir finished step s-1
        if (tid == 0) {
            const int target = NB * s;
            int guard = 0;
            while (__hip_atomic_load(ctrd, __ATOMIC_RELAXED, __HIP_MEMORY_SCOPE_AGENT) < target) {
                if (++guard > 100000000) break;   // safety valve vs hang
            }
            (void)__hip_atomic_load(ctrd, __ATOMIC_ACQUIRE, __HIP_MEMORY_SCOPE_AGENT);
        }
        if (tid < BB) ph_s[tid] = ph[tid * LL + t];
        __syncthreads();

        if (s) {
            // ---- stage H(prev) -> LDS bf16 hi/lo (swizzled), reset-zeroed ----
            {
                const float* __restrict__ Hp = Hd + ((s & 1) ^ 1) * (BB * DD);
                const int r  = tid >> 4;          // row == batch (== b)
                const int o  = (tid & 15) * 16;   // 16 consecutive k
                const bool rz = (dir != 0) && (t < lenb - 1);
                floatx4 a0 = {0,0,0,0}, a1 = {0,0,0,0}, a2 = {0,0,0,0}, a3 = {0,0,0,0};
                if (!rz) {
                    const floatx4* src = (const floatx4*)(Hp + r * DD + o);
                    a0 = src[0]; a1 = src[1]; a2 = src[2]; a3 = src[3];
                }
                // chunk 0: elems o..o+7 (a0,a1) ; chunk 1: o+8..o+15 (a2,a3)
                {
                    short8 sh, sl;
                    #pragma unroll
                    for (int e = 0; e < 4; ++e) {
                        float x = a0[e];
                        unsigned short hi = f2bf(x);
                        sh[e] = (short)hi; sl[e] = (short)f2bf(x - bf2f(hi));
                    }
                    #pragma unroll
                    for (int e = 0; e < 4; ++e) {
                        float x = a1[e];
                        unsigned short hi = f2bf(x);
                        sh[4 + e] = (short)hi; sl[4 + e] = (short)f2bf(x - bf2f(hi));
                    }
                    const int k8   = (o >> 3);
                    const int byte = ((r * 32 + k8) << 4) ^ ((r & 7) << 4);
                    *(short8*)((char*)Ahi + byte) = sh;
                    *(short8*)((char*)Alo + byte) = sl;
                }
                {
                    short8 sh, sl;
                    #pragma unroll
                    for (int e = 0; e < 4; ++e) {
                        float x = a2[e];
                        unsigned short hi = f2bf(x);
                        sh[e] = (short)hi; sl[e] = (short)f2bf(x - bf2f(hi));
                    }
                    #pragma unroll
                    for (int e = 0; e < 4; ++e) {
                        float x = a3[e];
                        unsigned short hi = f2bf(x);
                        sh[4 + e] = (short)hi; sl[4 + e] = (short)f2bf(x - bf2f(hi));
                    }
                    const int k8   = (o >> 3) + 1;
                    const int byte = ((r * 32 + k8) << 4) ^ ((r & 7) << 4);
                    *(short8*)((char*)Ahi + byte) = sh;
                    *(short8*)((char*)Alo + byte) = sl;
                }
            }
            __syncthreads();

            // ---- MFMA: this wave computes gate gt, m-tile mt, all 16 cols ----
            {
                floatx4 acc = {0.f, 0.f, 0.f, 0.f};
                const int row = mt * 16 + (lane & 15);
                const int swz = (row & 7) << 4;
                const int k8b = lane >> 4;
                #pragma unroll
                for (int kk = 0; kk < 8; ++kk) {
                    const int byte = ((row * 32 + kk * 4 + k8b) << 4) ^ swz;
                    short8 ah = *(const short8*)((const char*)Ahi + byte);
                    short8 al = *(const short8*)((const char*)Alo + byte);
                    acc = __builtin_amdgcn_mfma_f32_16x16x32_bf16(ah, bhi[kk], acc, 0, 0, 0);
                    acc = __builtin_amdgcn_mfma_f32_16x16x32_bf16(al, bhi[kk], acc, 0, 0, 0);
                    acc = __builtin_amdgcn_mfma_f32_16x16x32_bf16(ah, blo[kk], acc, 0, 0, 0);
                }
                const int bl = mt * 16 + (lane >> 4) * 4;
                #pragma unroll
                for (int r2 = 0; r2 < 4; ++r2) gl[gt][bl + r2][lane & 15] = acc[r2];
            }
            __syncthreads();
        }

        // ---- cell update: thread (b,dd) ----
        {
            const int v = ph_s[b];
            const float* __restrict__ trow = tb + (size_t)v * G4 + dglob;
            float xi  = trow[0];
            float xgg = trow[DD];
            float xf  = trow[2 * DD];
            float xo  = trow[3 * DD];
            if (s) {
                xi  += gl[0][b][dd];
                xgg += gl[1][b][dd];
                xf  += gl[2][b][dd];
                xo  += gl[3][b][dd];
            }
            if (dir && (t < lenb - 1)) c = 0.0f;   // hk.ResetCore: reset BEFORE step
            c = sigf(xf + 1.0f) * c + sigf(xi) * tanhf(xgg);
            const float h = sigf(xo) * tanhf(c);
            Hd[(s & 1) * (BB * DD) + b * DD + dglob] = h;
            float pr = h * wpd;
            pr += __shfl_xor(pr, 1, 16);
            pr += __shfl_xor(pr, 2, 16);
            pr += __shfl_xor(pr, 4, 16);
            pr += __shfl_xor(pr, 8, 16);
            if (dd == 0) pp[((size_t)(dir * NB + j) * BB + b) * LL + t] = pr;
        }
        __syncthreads();   // drain all stores before release
        if (tid == 0) __hip_atomic_fetch_add(ctrd, 1, __ATOMIC_RELEASE, __HIP_MEMORY_SCOPE_AGENT);
    }
}

// ---------------------------------------------------------------------------
// k_comb: out[b,t] = relu( sum over 32 (dir,j) partials + b_proj )
// ---------------------------------------------------------------------------
__global__ __launch_bounds__(256) void k_comb(
    const float* __restrict__ pp,
    const float* __restrict__ b_proj,
    float* __restrict__ out)
{
    const int i = blockIdx.x * 256 + threadIdx.x;   // i = b*LL + t
    float sv = b_proj[0];
    #pragma unroll
    for (int q = 0; q < 2 * NB; ++q) sv += pp[(size_t)q * (BB * LL) + i];
    out[i] = sv > 0.0f ? sv : 0.0f;
}

extern "C" void kernel_launch(void* const* d_in, const int* in_sizes, int n_in,
                              void* d_out, int out_size, void* d_ws, size_t ws_size,
                              hipStream_t stream)
{
    const int*   phon = (const int*)d_in[0];
    const int*   lens = (const int*)d_in[1];
    const float* emb  = (const float*)d_in[2];
    const float* wf   = (const float*)d_in[3];
    const float* bf   = (const float*)d_in[4];
    const float* wb   = (const float*)d_in[5];
    const float* bbi  = (const float*)d_in[6];
    const float* wp   = (const float*)d_in[7];
    const float* bp   = (const float*)d_in[8];
    float* out = (float*)d_out;

    float* ws  = (float*)d_ws;
    float* tbl = ws;                              // 2*256*1024      = 524288 f
    float* pp  = tbl + 2 * VOCAB * G4;            // 2*16*32*2048    = 2097152 f
    float* Hb  = pp + (size_t)2 * NB * BB * LL;   // 2*2*32*256      = 32768 f
    int*   ctr = (int*)(Hb + 2 * 2 * BB * DD);    // 2 ints

    k_zero  <<<1, 64, 0, stream>>>(ctr);
    k_table <<<2 * VOCAB, 256, 0, stream>>>(emb, wf, bf, wb, bbi, tbl);
    k_scan_b<<<2 * NB, TPB, 0, stream>>>(phon, lens, wf, wb, wp, tbl, Hb, pp, ctr);
    k_comb  <<<(BB * LL) / 256, 256, 0, stream>>>(pp, bp, out);
}

// Round 8
// 8001.901 us; speedup vs baseline: 2.0267x; 1.3255x over previous
//
#include <hip/hip_runtime.h>
#include <math.h>

#define VOCAB 256
#define DD    256     // hidden/embed dim
#define BB    32      // batch
#define LL    2048    // seq len
#define G4    1024    // 4*DD gate width
#define NB    16      // blocks per direction
#define TPB   512

typedef __attribute__((ext_vector_type(8))) short short8;
typedef __attribute__((ext_vector_type(4))) float floatx4;

__device__ __forceinline__ float sigf(float x) { return 1.0f / (1.0f + __expf(-x)); }

__device__ __forceinline__ unsigned short f2bf(float x) {
    unsigned u = __builtin_bit_cast(unsigned, x);
    u = u + 0x7fffu + ((u >> 16) & 1u);
    return (unsigned short)(u >> 16);
}
__device__ __forceinline__ float bf2f(unsigned short b) {
    unsigned u = ((unsigned)b) << 16;
    return __builtin_bit_cast(float, u);
}

// ---------------------------------------------------------------------------
// Kernel A: gates_table[dir][v][j] = sum_k embed[v][k] * w_dir[k][j] + b_dir[j]
// ---------------------------------------------------------------------------
__global__ __launch_bounds__(256) void k_table(
    const float* __restrict__ embed,
    const float* __restrict__ w_fwd, const float* __restrict__ b_fwd,
    const float* __restrict__ w_bwd, const float* __restrict__ b_bwd,
    float* __restrict__ tbl)
{
    const int dir = blockIdx.x >> 8;
    const int v   = blockIdx.x & 255;
    const float* __restrict__ w    = dir ? w_bwd : w_fwd;
    const float* __restrict__ bias = dir ? b_bwd : b_fwd;

    __shared__ __align__(16) float e[DD];
    const int tid = threadIdx.x;
    e[tid] = embed[v * DD + tid];
    __syncthreads();

    const float4* __restrict__ wx4 = (const float4*)w;  // [k][256] float4 groups
    float4 acc = ((const float4*)bias)[tid];
    #pragma unroll 2
    for (int k = 0; k < DD; k += 4) {
        float4 h4 = *(const float4*)&e[k];
        float4 w0 = wx4[(size_t)(k + 0) * 256 + tid];
        float4 w1 = wx4[(size_t)(k + 1) * 256 + tid];
        float4 w2 = wx4[(size_t)(k + 2) * 256 + tid];
        float4 w3 = wx4[(size_t)(k + 3) * 256 + tid];
        acc.x += h4.x * w0.x + h4.y * w1.x + h4.z * w2.x + h4.w * w3.x;
        acc.y += h4.x * w0.y + h4.y * w1.y + h4.z * w2.y + h4.w * w3.y;
        acc.z += h4.x * w0.z + h4.y * w1.z + h4.z * w2.z + h4.w * w3.z;
        acc.w += h4.x * w0.w + h4.y * w1.w + h4.z * w2.w + h4.w * w3.w;
    }
    ((float4*)tbl)[((size_t)dir * VOCAB + v) * 256 + tid] = acc;
}

// ---------------------------------------------------------------------------
// k_zero: reset the cross-block barrier counters (ws is poisoned each launch)
// ---------------------------------------------------------------------------
__global__ void k_zero(int* __restrict__ ctr) {
    ctr[threadIdx.x] = 0;   // 64 ints
}

// ---------------------------------------------------------------------------
// k_scan_b: batched bidirectional LSTM scan, relaxed-atomic sync (no L2
// invalidation). 32 blocks = 2 dirs x NB col-slices; block (dir,j) owns
// hidden dims [16j,16j+16) for all 32 batches; weight slice lives in VGPRs
// as bf16 hi/lo. Cross-block H exchange: packed (hi16|lo16) uint32 per dim,
// relaxed agent-scope atomics (sc1 per-access coherence, no cache flush).
// Counter protocol: bump AFTER __syncthreads (which drains vmcnt) => data
// at coherence point before flag moves; readers poll relaxed then read sc1.
// ---------------------------------------------------------------------------
__global__ __launch_bounds__(TPB, 2) void k_scan_b(
    const int*   __restrict__ ph,
    const int*   __restrict__ lens,
    const float* __restrict__ w_fwd,
    const float* __restrict__ w_bwd,
    const float* __restrict__ w_proj,
    const float* __restrict__ tbl,
    unsigned*    __restrict__ Hpk_all,
    float* __restrict__ pp,
    int*   __restrict__ ctr)
{
    const int dir  = blockIdx.x >> 4;
    const int j    = blockIdx.x & (NB - 1);
    const int tid  = threadIdx.x;
    const int lane = tid & 63;
    const int wv   = tid >> 6;        // wave 0..7
    const int mt   = wv >> 2;         // m-tile 0..1 (batches 16mt..16mt+15)
    const int gt   = wv & 3;          // gate 0..3 (i,g,f,o)

    const float* __restrict__ Wh = (dir ? w_bwd : w_fwd) + (size_t)DD * G4;
    const float* __restrict__ tb = tbl + (size_t)dir * VOCAB * G4;
    unsigned* __restrict__ Hpk = Hpk_all + (size_t)dir * 2 * BB * DD;
    int* ctrd = ctr + dir * 32;

    __shared__ unsigned short Ahi[BB * DD];   // 16KB, XOR-swizzled bf16 hi of H
    __shared__ unsigned short Alo[BB * DD];   // 16KB, lo
    __shared__ float gl[4][BB][17];           // padded: no bank aliasing
    // persistent cell state: this thread owns cell (b, dd)
    const int b     = tid >> 4;
    const int dd    = tid & 15;
    const int dglob = j * 16 + dd;
    float c = 0.0f;
    const int   lenb = lens[b];
    const float wpd  = w_proj[dir * DD + dglob];

    // ---- preload this wave's weight fragments into registers (bf16 split) ----
    short8 bhi[8], blo[8];
    {
        const int ccol  = gt * DD + j * 16 + (lane & 15);  // global gate column
        const int krow0 = 8 * (lane >> 4);
        #pragma unroll
        for (int kk = 0; kk < 8; ++kk) {
            short8 th, tl;
            #pragma unroll
            for (int e = 0; e < 8; ++e) {
                float wval = Wh[(size_t)(kk * 32 + krow0 + e) * G4 + ccol];
                unsigned short hi = f2bf(wval);
                th[e] = (short)hi;
                tl[e] = (short)f2bf(wval - bf2f(hi));
            }
            bhi[kk] = th;
            blo[kk] = tl;
        }
    }

    // ---- initial x-gate gather (s = 0) ----
    float xg0, xg1, xg2, xg3;
    {
        const int t0 = dir ? (LL - 1) : 0;
        const int v  = ph[b * LL + t0];
        const float* __restrict__ trow = tb + (size_t)v * G4 + dglob;
        xg0 = trow[0]; xg1 = trow[DD]; xg2 = trow[2 * DD]; xg3 = trow[3 * DD];
    }

    for (int s = 0; s < LL; ++s) {
        const int t = dir ? (LL - 1 - s) : s;

        if (s) {
            // ---- poll: all NB blocks of this dir finished step s-1 ----
            if (tid == 0) {
                const int target = NB * s;
                int guard = 0;
                while (__hip_atomic_load(ctrd, __ATOMIC_RELAXED, __HIP_MEMORY_SCOPE_AGENT) < target) {
                    __builtin_amdgcn_s_sleep(1);
                    if (++guard > 200000000) break;   // safety valve vs hang
                }
            }
            __syncthreads();

            // ---- stage H(prev) -> LDS bf16 hi/lo planes (swizzled) ----
            {
                const int r = tid >> 4;          // row == batch (== b)
                const int o = (tid & 15) * 16;   // 16 consecutive k dims
                const bool rz = (dir != 0) && (t < lenb - 1);   // reset: h==0
                unsigned long long u[8];
                unsigned long long* src = (unsigned long long*)
                    (Hpk + ((s & 1) ^ 1) * (BB * DD) + r * DD + o);
                #pragma unroll
                for (int e = 0; e < 8; ++e)
                    u[e] = __hip_atomic_load(src + e, __ATOMIC_RELAXED, __HIP_MEMORY_SCOPE_AGENT);
                if (rz) {
                    #pragma unroll
                    for (int e = 0; e < 8; ++e) u[e] = 0ull;
                }
                // chunk 0: dims o..o+7 (u[0..3]) ; chunk 1: o+8..o+15 (u[4..7])
                #pragma unroll
                for (int hchunk = 0; hchunk < 2; ++hchunk) {
                    short8 sh, sl;
                    #pragma unroll
                    for (int e = 0; e < 4; ++e) {
                        const unsigned long long ue = u[4 * hchunk + e];
                        const unsigned lo32 = (unsigned)ue;
                        const unsigned hi32 = (unsigned)(ue >> 32);
                        sh[2 * e]     = (short)(lo32 >> 16);
                        sl[2 * e]     = (short)(lo32 & 0xffffu);
                        sh[2 * e + 1] = (short)(hi32 >> 16);
                        sl[2 * e + 1] = (short)(hi32 & 0xffffu);
                    }
                    const int k8   = (o >> 3) + hchunk;
                    const int byte = ((r * 32 + k8) << 4) ^ ((r & 7) << 4);
                    *(short8*)((char*)Ahi + byte) = sh;
                    *(short8*)((char*)Alo + byte) = sl;
                }
            }
            __syncthreads();

            // ---- MFMA: wave computes gate gt, m-tile mt, 16 cols ----
            {
                floatx4 acc = {0.f, 0.f, 0.f, 0.f};
                const int row = mt * 16 + (lane & 15);
                const int swz = (row & 7) << 4;
                const int k8b = lane >> 4;
                #pragma unroll
                for (int kk = 0; kk < 8; ++kk) {
                    const int byte = ((row * 32 + kk * 4 + k8b) << 4) ^ swz;
                    short8 ah = *(const short8*)((const char*)Ahi + byte);
                    short8 al = *(const short8*)((const char*)Alo + byte);
                    acc = __builtin_amdgcn_mfma_f32_16x16x32_bf16(ah, bhi[kk], acc, 0, 0, 0);
                    acc = __builtin_amdgcn_mfma_f32_16x16x32_bf16(al, bhi[kk], acc, 0, 0, 0);
                    acc = __builtin_amdgcn_mfma_f32_16x16x32_bf16(ah, blo[kk], acc, 0, 0, 0);
                }
                const int bl = mt * 16 + (lane >> 4) * 4;
                #pragma unroll
                for (int r2 = 0; r2 < 4; ++r2) gl[gt][bl + r2][lane & 15] = acc[r2];
            }
            __syncthreads();
        }

        // ---- cell update: thread (b,dd) ----
        float h;
        {
            float xi  = xg0;
            float xgg = xg1;
            float xf  = xg2;
            float xo  = xg3;
            if (s) {
                xi  += gl[0][b][dd];
                xgg += gl[1][b][dd];
                xf  += gl[2][b][dd];
                xo  += gl[3][b][dd];
            }
            if (dir && (t < lenb - 1)) c = 0.0f;   // hk.ResetCore: reset BEFORE step
            c = sigf(xf + 1.0f) * c + sigf(xi) * tanhf(xgg);
            h = sigf(xo) * tanhf(c);
            const unsigned short hhi = f2bf(h);
            const unsigned short hlo = f2bf(h - bf2f(hhi));
            const unsigned upk = ((unsigned)hhi << 16) | (unsigned)hlo;
            __hip_atomic_store(Hpk + (s & 1) * (BB * DD) + b * DD + dglob, upk,
                               __ATOMIC_RELAXED, __HIP_MEMORY_SCOPE_AGENT);
        }
        __syncthreads();   // drains vmcnt: h stores at coherence point
        if (tid == 0)
            __hip_atomic_fetch_add(ctrd, 1, __ATOMIC_RELAXED, __HIP_MEMORY_SCOPE_AGENT);

        // ---- off-critical-path: projection partial + next-step gather ----
        {
            float pr = h * wpd;
            pr += __shfl_xor(pr, 1, 16);
            pr += __shfl_xor(pr, 2, 16);
            pr += __shfl_xor(pr, 4, 16);
            pr += __shfl_xor(pr, 8, 16);
            if (dd == 0) pp[((size_t)(dir * NB + j) * BB + b) * LL + t] = pr;
        }
        if (s + 1 < LL) {
            const int tn = dir ? (LL - 2 - s) : (s + 1);
            const int v  = ph[b * LL + tn];
            const float* __restrict__ trow = tb + (size_t)v * G4 + dglob;
            xg0 = trow[0]; xg1 = trow[DD]; xg2 = trow[2 * DD]; xg3 = trow[3 * DD];
        }
    }
}

// ---------------------------------------------------------------------------
// k_comb: out[b,t] = relu( sum over 32 (dir,j) partials + b_proj )
// ---------------------------------------------------------------------------
__global__ __launch_bounds__(256) void k_comb(
    const float* __restrict__ pp,
    const float* __restrict__ b_proj,
    float* __restrict__ out)
{
    const int i = blockIdx.x * 256 + threadIdx.x;   // i = b*LL + t
    float sv = b_proj[0];
    #pragma unroll
    for (int q = 0; q < 2 * NB; ++q) sv += pp[(size_t)q * (BB * LL) + i];
    out[i] = sv > 0.0f ? sv : 0.0f;
}

extern "C" void kernel_launch(void* const* d_in, const int* in_sizes, int n_in,
                              void* d_out, int out_size, void* d_ws, size_t ws_size,
                              hipStream_t stream)
{
    const int*   phon = (const int*)d_in[0];
    const int*   lens = (const int*)d_in[1];
    const float* emb  = (const float*)d_in[2];
    const float* wf   = (const float*)d_in[3];
    const float* bf   = (const float*)d_in[4];
    const float* wb   = (const float*)d_in[5];
    const float* bbi  = (const float*)d_in[6];
    const float* wp   = (const float*)d_in[7];
    const float* bp   = (const float*)d_in[8];
    float* out = (float*)d_out;

    float*    ws  = (float*)d_ws;
    float*    tbl = ws;                               // 2*256*1024   f (2 MB)
    float*    pp  = tbl + 2 * VOCAB * G4;             // 2*16*32*2048 f (8 MB)
    unsigned* Hpk = (unsigned*)(pp + (size_t)2 * NB * BB * LL);  // 2*2*32*256 u32 (128 KB)
    int*      ctr = (int*)(Hpk + 2 * 2 * BB * DD);    // 64 ints (dir*32 stride)

    k_zero  <<<1, 64, 0, stream>>>(ctr);
    k_table <<<2 * VOCAB, 256, 0, stream>>>(emb, wf, bf, wb, bbi, tbl);
    k_scan_b<<<2 * NB, TPB, 0, stream>>>(phon, lens, wf, wb, wp, tbl, Hpk, pp, ctr);
    k_comb  <<<(BB * LL) / 256, 256, 0, stream>>>(pp, bp, out);
}